// Round 1
// baseline (101.245 us; speedup 1.0000x reference)
//
#include <hip/hip_runtime.h>

// Problem constants
#define BATCH 16384
#define ZDIM  256
#define NCLS  1000
#define NPAD  1024

typedef __bf16 bf16x8 __attribute__((ext_vector_type(8)));
typedef float  f32x4  __attribute__((ext_vector_type(4)));

// Workspace layout (bytes):
//   xb  : bf16[BATCH*ZDIM]          @ 0         (8,388,608 B)
//   cb  : bf16[NPAD*ZDIM]           @ 8388608   (524,288 B)
//   xsq : float[BATCH]              @ 8912896   (65,536 B)
//   csq : float[NPAD]               @ 8978432   (4,096 B)
//   acc : float[1]                  @ 8982528
#define WS_XB   0
#define WS_CB   8388608
#define WS_XSQ  8912896
#define WS_CSQ  8978432
#define WS_ACC  8982528

__device__ __forceinline__ unsigned short f2bf(float f) {
    union { float f; unsigned int u; } v; v.f = f;
    unsigned int u = v.u;
    unsigned int r = (u + 0x7fffu + ((u >> 16) & 1u)) >> 16;   // RNE
    return (unsigned short)r;
}

// Cast x -> bf16, compute per-row ||x||^2. One wave per row, 4 rows/block.
__global__ void prep_x(const float* __restrict__ x,
                       unsigned short* __restrict__ xb,
                       float* __restrict__ xsq,
                       float* __restrict__ acc) {
    const int wid  = threadIdx.x >> 6;
    const int lane = threadIdx.x & 63;
    const int row  = blockIdx.x * 4 + wid;

    const float4 v = *(const float4*)(x + (size_t)row * ZDIM + lane * 4);
    ushort4 b;
    b.x = f2bf(v.x); b.y = f2bf(v.y); b.z = f2bf(v.z); b.w = f2bf(v.w);
    *(ushort4*)(xb + (size_t)row * ZDIM + lane * 4) = b;

    float s = v.x * v.x + v.y * v.y + v.z * v.z + v.w * v.w;
    #pragma unroll
    for (int off = 32; off; off >>= 1) s += __shfl_down(s, off);
    if (lane == 0) xsq[row] = s;

    if (blockIdx.x == 0 && threadIdx.x == 0) *acc = 0.0f;
}

// Cast centers -> bf16 padded to NPAD rows (zeros), compute per-row ||c||^2.
__global__ void prep_c(const float* __restrict__ centers,
                       unsigned short* __restrict__ cb,
                       float* __restrict__ csq) {
    const int wid  = threadIdx.x >> 6;
    const int lane = threadIdx.x & 63;
    const int row  = blockIdx.x * 4 + wid;

    if (row < NCLS) {
        const float4 v = *(const float4*)(centers + (size_t)row * ZDIM + lane * 4);
        ushort4 b;
        b.x = f2bf(v.x); b.y = f2bf(v.y); b.z = f2bf(v.z); b.w = f2bf(v.w);
        *(ushort4*)(cb + (size_t)row * ZDIM + lane * 4) = b;
        float s = v.x * v.x + v.y * v.y + v.z * v.z + v.w * v.w;
        #pragma unroll
        for (int off = 32; off; off >>= 1) s += __shfl_down(s, off);
        if (lane == 0) csq[row] = s;
    } else {
        ushort4 z; z.x = z.y = z.z = z.w = 0;
        *(ushort4*)(cb + (size_t)row * ZDIM + lane * 4) = z;
        if (lane == 0) csq[row] = 0.0f;
    }
}

#define GLOAD_LDS(gp, lp)                                                     \
    __builtin_amdgcn_global_load_lds(                                         \
        (__attribute__((address_space(1))) const void*)(gp),                  \
        (__attribute__((address_space(3))) void*)(lp), 16, 0, 0)

// Fused GEMM + distance + mask + reduce.
// 128x128 tile per block, 256 threads (4 waves, 2x2), BK=32, 16x16x32 bf16 MFMA.
__global__ __launch_bounds__(256) void gemm_loss(
        const unsigned short* __restrict__ xb,
        const unsigned short* __restrict__ cb,
        const float* __restrict__ xsq,
        const float* __restrict__ csq,
        const int* __restrict__ labels,
        float* __restrict__ acc) {
    __shared__ unsigned short As[128 * 32];   // 8 KB, row-major [row][k], k-stride 32
    __shared__ unsigned short Bs[128 * 32];   // 8 KB
    __shared__ float xsq_s[128];
    __shared__ float csq_s[128];
    __shared__ int   lab_s[128];
    __shared__ float wsum[4];

    const int tid  = threadIdx.x;
    const int lane = tid & 63;
    const int wid  = tid >> 6;
    const int bm   = blockIdx.x >> 3;      // 0..127
    const int bn   = blockIdx.x & 7;       // 0..7
    const int m0   = bm * 128;
    const int n0   = bn * 128;

    if (tid < 128) {
        xsq_s[tid] = xsq[m0 + tid];
        lab_s[tid] = labels[m0 + tid];
    } else {
        const int t = tid - 128;
        csq_s[t] = csq[n0 + t];
    }

    const int wm = wid & 1;      // wave row (0/1) -> 64 rows
    const int wn = wid >> 1;     // wave col (0/1) -> 64 cols

    f32x4 acc_r[4][4];
    #pragma unroll
    for (int i = 0; i < 4; ++i)
        #pragma unroll
        for (int j = 0; j < 4; ++j) {
            f32x4 z = {0.0f, 0.0f, 0.0f, 0.0f};
            acc_r[i][j] = z;
        }

    // staging: 512 16B-chunks per tile; chunk c -> row c>>2, k-offset (c&3)*8
    const int c0 = tid;            // 0..255
    const int c1 = 256 + tid;      // 256..511
    const int rowA0 = c0 >> 2, kc0 = (c0 & 3) * 8;
    const int rowA1 = c1 >> 2, kc1 = (c1 & 3) * 8;
    const unsigned short* ga0 = xb + (size_t)(m0 + rowA0) * ZDIM + kc0;
    const unsigned short* ga1 = xb + (size_t)(m0 + rowA1) * ZDIM + kc1;
    const unsigned short* gb0 = cb + (size_t)(n0 + rowA0) * ZDIM + kc0;
    const unsigned short* gb1 = cb + (size_t)(n0 + rowA1) * ZDIM + kc1;

    const int quad = lane >> 4;          // 0..3 -> k-offset quad*8
    const int lr   = lane & 15;          // row/col within 16-tile

    #pragma unroll
    for (int ki = 0; ki < 8; ++ki) {
        const int k0 = ki * 32;
        GLOAD_LDS(ga0 + k0, &As[c0 * 8]);
        GLOAD_LDS(ga1 + k0, &As[c1 * 8]);
        GLOAD_LDS(gb0 + k0, &Bs[c0 * 8]);
        GLOAD_LDS(gb1 + k0, &Bs[c1 * 8]);
        __syncthreads();

        bf16x8 af[4], bf[4];
        #pragma unroll
        for (int i = 0; i < 4; ++i) {
            const int r = wm * 64 + i * 16 + lr;
            af[i] = *(const bf16x8*)&As[r * 32 + quad * 8];
            const int c = wn * 64 + i * 16 + lr;
            bf[i] = *(const bf16x8*)&Bs[c * 32 + quad * 8];
        }
        #pragma unroll
        for (int i = 0; i < 4; ++i)
            #pragma unroll
            for (int j = 0; j < 4; ++j)
                acc_r[i][j] = __builtin_amdgcn_mfma_f32_16x16x32_bf16(
                    af[i], bf[j], acc_r[i][j], 0, 0, 0);
        __syncthreads();
    }

    // Epilogue: dist -> sqrt -> clamp -> mask (label & pad) -> sum
    // C/D layout (16x16): col = lane&15, row = (lane>>4)*4 + reg  [m89/m91]
    float sum = 0.0f;
    #pragma unroll
    for (int j = 0; j < 4; ++j) {
        const int col_l = wn * 64 + j * 16 + lr;
        const int col_g = n0 + col_l;
        const float cs = csq_s[col_l];
        const bool colok = (col_g < NCLS);
        #pragma unroll
        for (int i = 0; i < 4; ++i) {
            #pragma unroll
            for (int r = 0; r < 4; ++r) {
                const int row_l = wm * 64 + i * 16 + quad * 4 + r;
                float dist = xsq_s[row_l] + cs - 2.0f * acc_r[i][j][r];
                float d = sqrtf(fmaxf(dist, 0.0f));
                d = fminf(fmaxf(d, 1e-8f), 1e8f);
                if (colok && (lab_s[row_l] != col_g)) sum += d;
            }
        }
    }

    #pragma unroll
    for (int off = 32; off; off >>= 1) sum += __shfl_down(sum, off);
    if (lane == 0) wsum[wid] = sum;
    __syncthreads();
    if (tid == 0) atomicAdd(acc, wsum[0] + wsum[1] + wsum[2] + wsum[3]);
}

__global__ void finalize(const float* __restrict__ acc, float* __restrict__ out) {
    out[0] = acc[0] * (1.0f / (16384.0f * 999.0f));
}

extern "C" void kernel_launch(void* const* d_in, const int* in_sizes, int n_in,
                              void* d_out, int out_size, void* d_ws, size_t ws_size,
                              hipStream_t stream) {
    const float* x       = (const float*)d_in[0];
    const float* centers = (const float*)d_in[1];
    const int*   labels  = (const int*)d_in[2];
    float*       out     = (float*)d_out;

    char* ws = (char*)d_ws;
    unsigned short* xb  = (unsigned short*)(ws + WS_XB);
    unsigned short* cb  = (unsigned short*)(ws + WS_CB);
    float*          xsq = (float*)(ws + WS_XSQ);
    float*          csq = (float*)(ws + WS_CSQ);
    float*          acc = (float*)(ws + WS_ACC);

    prep_x<<<BATCH / 4, 256, 0, stream>>>(x, xb, xsq, acc);
    prep_c<<<NPAD / 4, 256, 0, stream>>>(centers, cb, csq);
    gemm_loss<<<(BATCH / 128) * (NPAD / 128), 256, 0, stream>>>(
        xb, cb, xsq, csq, labels, acc);
    finalize<<<1, 1, 0, stream>>>(acc, out);
}